// Round 6
// baseline (411.747 us; speedup 1.0000x reference)
//
#include <hip/hip_runtime.h>
#include <stdint.h>

// B=4, T=2048, C=1024, H=16, D=64, R=32
// Pipeline: cvt -> qkv3_gemm(fused QKV, dbuf) -> attn(ZERO-LDS: direct-from-L2
//   K/V fragments, in-register P, barrier-free) -> out_gemm(dbuf)

typedef __attribute__((ext_vector_type(8))) short bf16x8;   // 8 bf16 (4 VGPRs)
typedef __attribute__((ext_vector_type(4))) float f32x4;    // MFMA accumulator
typedef __attribute__((ext_vector_type(4))) short short4v;  // 8-byte packed load/store

#define MFMA16(a, b, c) __builtin_amdgcn_mfma_f32_16x16x32_bf16((a), (b), (c), 0, 0, 0)

#if __has_builtin(__builtin_amdgcn_exp2f)
#define FEXP(x) __builtin_amdgcn_exp2f(x)
#define QSCALE 0.18033688011112042f  // 0.125 * log2(e)
#else
#define FEXP(x) __expf(x)
#define QSCALE 0.125f
#endif

static __device__ __forceinline__ short f2bf(float f) {
  union { float fv; uint32_t u; } v; v.fv = f;
  uint32_t r = v.u + 0x7FFFu + ((v.u >> 16) & 1u);  // RNE
  return (short)(r >> 16);
}

// pack two fp32 -> two bf16 (truncation) in one v_perm_b32
static __device__ __forceinline__ uint32_t pack_trunc(float a, float b) {
  union { float f; uint32_t u; } ua, ub;
  ua.f = a; ub.f = b;
#if __has_builtin(__builtin_amdgcn_perm)
  return __builtin_amdgcn_perm(ub.u, ua.u, 0x07060302u);
#else
  return (ub.u & 0xFFFF0000u) | (ua.u >> 16);
#endif
}

typedef __attribute__((address_space(1))) void as1_void;
typedef __attribute__((address_space(3))) void as3_void;
static __device__ __forceinline__ void gld_lds16(const void* g, void* l) {
  __builtin_amdgcn_global_load_lds((as1_void*)g, (as3_void*)l, 16, 0, 0);
}

// ---------------------------------------------------------------------------
// Kernel 1: fp32 -> bf16 conversion for x, Wq, Wk, Wv, Wo
// ---------------------------------------------------------------------------
__global__ __launch_bounds__(256) void cvt_kernel(
    const float* x, const float* wq, const float* wk, const float* wv,
    const float* wo,
    short* xb, short* wqb, short* wkb, short* wvb, short* wob) {
  int64_t g = (int64_t)blockIdx.x * 256 + threadIdx.x;  // unit = 4 floats
  const int64_t NX = 8388608 / 4, NW = 1048576 / 4;
  const float* src;
  short* dst;
  int64_t i;
  if (g < NX)               { src = x;  dst = xb;  i = g; }
  else if (g < NX + NW)     { src = wq; dst = wqb; i = g - NX; }
  else if (g < NX + 2 * NW) { src = wk; dst = wkb; i = g - NX - NW; }
  else if (g < NX + 3 * NW) { src = wv; dst = wvb; i = g - NX - 2 * NW; }
  else                      { src = wo; dst = wob; i = g - NX - 3 * NW; }
  float4 v = ((const float4*)src)[i];
  short4v o;
  o[0] = f2bf(v.x); o[1] = f2bf(v.y); o[2] = f2bf(v.z); o[3] = f2bf(v.w);
  *(short4v*)&dst[i * 4] = o;
}

// ---------------------------------------------------------------------------
// Kernel 2: fused QKV projection (M=8192, N=1024 x3, K=1024), BK=32.
//   One A-tile stage feeds 3 B-tiles: 48 MFMA per barrier. Double-buffered
//   staging issued right after the barrier.
//   Q: scaled by QSCALE; K,V: masked rows zeroed.
//   Q,K written [bh][t][64] bf16; V written [bh][64][t] bf16 (transposed).
// ---------------------------------------------------------------------------
__global__ __launch_bounds__(256, 2) void qkv3_gemm(
    const short* __restrict__ Xb,
    const short* __restrict__ Wq, const short* __restrict__ Wk,
    const short* __restrict__ Wv,
    const float* __restrict__ bq, const float* __restrict__ bk,
    const float* __restrict__ bv,
    const float* __restrict__ rope, const int* __restrict__ mask,
    short* __restrict__ Qh, short* __restrict__ Kh, short* __restrict__ Vt) {
  __shared__ __align__(16) short As[2][128 * 32];     // 16 KB
  __shared__ __align__(16) short Bs[2][3][128 * 32];  // 48 KB

  const int t = threadIdx.x;
  const int lane = t & 63;
  const int wave = t >> 6;
  const int c = lane & 15;
  const int quad = lane >> 4;
  const int m0 = blockIdx.x * 128;
  const int n0 = blockIdx.y * 128;

  f32x4 zero4 = {0.f, 0.f, 0.f, 0.f};
  f32x4 acc[3][4][4];
#pragma unroll
  for (int m = 0; m < 3; ++m)
#pragma unroll
    for (int i = 0; i < 4; ++i)
#pragma unroll
      for (int j = 0; j < 4; ++j) acc[m][i][j] = zero4;

  const int wm = wave & 1, wn = wave >> 1;

  const int srow = t >> 2;
  const int gc = ((t & 3) - (srow >> 2)) & 3;
  const short* gA = Xb + (size_t)(m0 + srow) * 1024 + gc * 8;
  const short* gW0 = Wq + (size_t)(n0 + srow) * 1024 + gc * 8;
  const short* gW1 = Wk + (size_t)(n0 + srow) * 1024 + gc * 8;
  const short* gW2 = Wv + (size_t)(n0 + srow) * 1024 + gc * 8;

#define QKV_STAGE(buf, k0)                                  \
  do {                                                      \
    gld_lds16(gA + (k0), &As[buf][t * 8]);                  \
    gld_lds16(gA + (k0) + 65536, &As[buf][t * 8 + 2048]);   \
    gld_lds16(gW0 + (k0), &Bs[buf][0][t * 8]);              \
    gld_lds16(gW0 + (k0) + 65536, &Bs[buf][0][t * 8 + 2048]); \
    gld_lds16(gW1 + (k0), &Bs[buf][1][t * 8]);              \
    gld_lds16(gW1 + (k0) + 65536, &Bs[buf][1][t * 8 + 2048]); \
    gld_lds16(gW2 + (k0), &Bs[buf][2][t * 8]);              \
    gld_lds16(gW2 + (k0) + 65536, &Bs[buf][2][t * 8 + 2048]); \
  } while (0)

  QKV_STAGE(0, 0);

  for (int ki = 0; ki < 32; ++ki) {
    __syncthreads();  // drains buf[ki&1] loads (issued one compute phase ago)
    if (ki < 31) QKV_STAGE((ki + 1) & 1, (ki + 1) * 32);

    const short* as = &As[ki & 1][0];
    bf16x8 af[4];
#pragma unroll
    for (int i = 0; i < 4; ++i) {
      int mr = wm * 64 + i * 16 + c;
      af[i] = *(const bf16x8*)&as[mr * 32 + (((quad + (mr >> 2)) & 3) * 8)];
    }
#pragma unroll
    for (int m = 0; m < 3; ++m) {
      const short* bs = &Bs[ki & 1][m][0];
      bf16x8 bfr[4];
#pragma unroll
      for (int j = 0; j < 4; ++j) {
        int nr = wn * 64 + j * 16 + c;
        bfr[j] = *(const bf16x8*)&bs[nr * 32 + (((quad + (nr >> 2)) & 3) * 8)];
      }
#pragma unroll
      for (int i = 0; i < 4; ++i)
#pragma unroll
        for (int j = 0; j < 4; ++j)
          acc[m][i][j] = MFMA16(af[i], bfr[j], acc[m][i][j]);
    }
  }
#undef QKV_STAGE

  // ---- epilogue: C/D layout col=lane&15, row=quad*4+reg ----
  const int nb = n0 + wn * 64;  // wave's 64 cols == one head
  const int hcol = nb >> 6;
  const int bidx = m0 >> 11;
  const int tbase = (m0 & 2047) + wm * 64 + quad * 4;
  const int* mrow = mask + bidx * 2048;

  // Q (mat 0) and K (mat 1): [bh][t][64] with RoPE
#pragma unroll
  for (int mat = 0; mat < 2; ++mat) {
    short* Og = (mat == 0) ? Qh : Kh;
    const float* bias = (mat == 0) ? bq : bk;
    float bj[4];
#pragma unroll
    for (int j = 0; j < 4; ++j) bj[j] = bias[nb + j * 16 + c];
    size_t hb = (size_t)(bidx * 16 + hcol) * 2048;
#pragma unroll
    for (int i = 0; i < 4; ++i) {
#pragma unroll
      for (int r = 0; r < 4; ++r) {
        int tp = tbase + i * 16 + r;
        float f = (mat == 0) ? QSCALE : (mrow[tp] ? 1.0f : 0.0f);
        float cosv = rope[tp * 32 + c];
        float sinv = rope[65536 + tp * 32 + c];
        float v0 = acc[mat][i][0][r] + bj[0];
        float v1 = acc[mat][i][1][r] + bj[1];
        float v2 = acc[mat][i][2][r] + bj[2];
        float v3 = acc[mat][i][3][r] + bj[3];
        size_t base = (hb + tp) * 64;
        Og[base + c]      = f2bf((v0 * cosv - v1 * sinv) * f);
        Og[base + 16 + c] = f2bf((v1 * cosv + v0 * sinv) * f);
        Og[base + 32 + c] = f2bf(v2 * f);
        Og[base + 48 + c] = f2bf(v3 * f);
      }
    }
  }
  // V (mat 2): transposed [bh][d][t], masked t zeroed
  {
    float bj[4];
#pragma unroll
    for (int j = 0; j < 4; ++j) bj[j] = bv[nb + j * 16 + c];
    size_t hb = (size_t)(bidx * 16 + hcol) * 64;
#pragma unroll
    for (int i = 0; i < 4; ++i) {
      int tp = tbase + i * 16;  // multiple of 4
      int4 mv = *(const int4*)&mrow[tp];
      float fr[4];
      fr[0] = mv.x ? 1.f : 0.f; fr[1] = mv.y ? 1.f : 0.f;
      fr[2] = mv.z ? 1.f : 0.f; fr[3] = mv.w ? 1.f : 0.f;
#pragma unroll
      for (int j = 0; j < 4; ++j) {
        short4v pv;
#pragma unroll
        for (int r = 0; r < 4; ++r)
          pv[r] = f2bf((acc[2][i][j][r] + bj[j]) * fr[r]);
        size_t base = (hb + j * 16 + c) * 2048 + tp;
        *(short4v*)&Vt[base] = pv;
      }
    }
  }
}

// ---------------------------------------------------------------------------
// Kernel 3: attention, static softmax, ZERO-LDS (round-6 rewrite).
//   K/V for one head = 512 KB, L2-resident on this block's XCD (bh-major
//   grid). So fragments are loaded DIRECTLY from global/L2 — no staging,
//   no LDS, no barriers, no bank conflicts; waves free-run independently.
//   ak (16B contiguous) and av (2x 8B contiguous) addresses are clean because
//   the k-slot permutation k_phys(kappa=quad*8+j) is a pure function of the
//   hardware k-index (same for P's B-fragment built in-register from St).
//   K fragments double-buffered in registers (1-chunk prefetch, covered by
//   a full chunk of compute); V fragments just-in-time (covered by QK^T+exp).
//   Uniform chunk offsets separated so loads use SGPR-base + invariant voffset.
//   4 waves x 64 q-rows; grid (64 heads, 8 qt).
// ---------------------------------------------------------------------------
__global__ __launch_bounds__(256, 2) void attn_kernel(
    const short* __restrict__ Qh, const short* __restrict__ Kh,
    const short* __restrict__ Vt, const int* __restrict__ mask,
    short* __restrict__ Og) {
  const int t = threadIdx.x;
  const int lane = t & 63;
  const int wave = t >> 6;  // 0..3
  const int c = lane & 15;
  const int quad = lane >> 4;
  const int bh = blockIdx.x;   // 0..63 (x-major: head -> fixed XCD)
  const int qt = blockIdx.y;   // 0..7 (256 q rows each)
  const int bidx = bh >> 4;
  const short* Qg = Qh + ((size_t)bh * 2048 + qt * 256) * 64;
  const short* Kg = Kh + (size_t)bh * 2048 * 64;
  const short* Vg = Vt + (size_t)bh * 64 * 2048;

  // count masked keys for this batch; full butterfly so every lane holds the
  // total (in-register)
  float nm;
  {
    const int4* mr = (const int4*)(mask + bidx * 2048);
    int cnt = 0;
#pragma unroll
    for (int k = 0; k < 8; ++k) {
      int4 a = mr[k * 64 + lane];
      cnt += (a.x == 0) + (a.y == 0) + (a.z == 0) + (a.w == 0);
    }
    cnt += __shfl_xor(cnt, 1);  cnt += __shfl_xor(cnt, 2);
    cnt += __shfl_xor(cnt, 4);  cnt += __shfl_xor(cnt, 8);
    cnt += __shfl_xor(cnt, 16); cnt += __shfl_xor(cnt, 32);
    nm = (float)cnt;
  }

  // Q fragments (B-operand), loop-invariant; wave covers 64 q rows (it 0..3)
  bf16x8 qf[2][4];
#pragma unroll
  for (int ks = 0; ks < 2; ++ks)
#pragma unroll
    for (int it = 0; it < 4; ++it)
      qf[ks][it] =
          *(const bf16x8*)&Qg[(wave * 64 + it * 16 + c) * 64 + ks * 32 + quad * 8];

  const bf16x8 ones = {0x3F80, 0x3F80, 0x3F80, 0x3F80,
                       0x3F80, 0x3F80, 0x3F80, 0x3F80};  // bf16 1.0 x8

  f32x4 zero4 = {0.f, 0.f, 0.f, 0.f};
  f32x4 O[4][4];
#pragma unroll
  for (int dt = 0; dt < 4; ++dt)
#pragma unroll
    for (int it = 0; it < 4; ++it) O[dt][it] = zero4;
  f32x4 Ol[4] = {zero4, zero4, zero4, zero4};

  // K-fragment register double buffer: prologue loads chunk 0 into set A.
  bf16x8 akA[2][4], akB[2][4];
#pragma unroll
  for (int ks = 0; ks < 2; ++ks)
#pragma unroll
    for (int jt = 0; jt < 4; ++jt)
      akA[ks][jt] =
          *(const bf16x8*)&Kg[(jt * 16 + c) * 64 + ks * 32 + quad * 8];

  for (int cb = 0; cb < 32; cb += 2) {
#pragma unroll
    for (int ph = 0; ph < 2; ++ph) {
      const int ci = cb + ph;
      bf16x8(&cur)[2][4] = ph ? akB : akA;   // compile-time after unroll
      bf16x8(&nxt)[2][4] = ph ? akA : akB;

      // prefetch next chunk's K fragments (a full chunk of compute to land)
      if (ci < 31) {
        const short* kn = Kg + (size_t)(ci + 1) * 4096;  // uniform term
#pragma unroll
        for (int ks = 0; ks < 2; ++ks)
#pragma unroll
          for (int jt = 0; jt < 4; ++jt)
            nxt[ks][jt] = *(const bf16x8*)&kn[(jt * 16 + c) * 64 +
                                              ks * 32 + quad * 8];
      }

      // V fragments just-in-time (first use is after QK^T + exp ~600cy).
      // Slot j of av[ks][dt] = V^T[dt*16+c][k_phys], k_phys = kappa-mapped:
      // lo (j=0..3): ks*32+quad*4+{0..3}; hi (j=4..7): +16. Contiguous 8B each.
      const short* vc = Vg + ci * 64;  // uniform term
      bf16x8 av[2][4];
#pragma unroll
      for (int ks = 0; ks < 2; ++ks)
#pragma unroll
        for (int dt = 0; dt < 4; ++dt) {
          union { short4v h[2]; bf16x8 v; } uu;
          uu.h[0] = *(const short4v*)&vc[(dt * 16 + c) * 2048 +
                                         ks * 32 + quad * 4];
          uu.h[1] = *(const short4v*)&vc[(dt * 16 + c) * 2048 +
                                         ks * 32 + 16 + quad * 4];
          av[ks][dt] = uu.v;
        }

#pragma unroll
      for (int it = 0; it < 4; ++it) {  // four 16-row q sub-blocks
        f32x4 St[4];
#pragma unroll
        for (int jt = 0; jt < 4; ++jt)
          St[jt] = MFMA16(cur[0][jt], qf[0][it], zero4);
#pragma unroll
        for (int jt = 0; jt < 4; ++jt)
          St[jt] = MFMA16(cur[1][jt], qf[1][it], St[jt]);

        // exp2 + pack -> PV B-fragments, entirely in-register.
        bf16x8 bp[2];
#pragma unroll
        for (int ks = 0; ks < 2; ++ks) {
          union { uint32_t w[4]; bf16x8 v; } uu;
          uu.w[0] = pack_trunc(FEXP(St[2 * ks][0]),     FEXP(St[2 * ks][1]));
          uu.w[1] = pack_trunc(FEXP(St[2 * ks][2]),     FEXP(St[2 * ks][3]));
          uu.w[2] = pack_trunc(FEXP(St[2 * ks + 1][0]), FEXP(St[2 * ks + 1][1]));
          uu.w[3] = pack_trunc(FEXP(St[2 * ks + 1][2]), FEXP(St[2 * ks + 1][3]));
          bp[ks] = uu.v;
        }

#pragma unroll
        for (int ks = 0; ks < 2; ++ks) {
          Ol[it] = MFMA16(ones, bp[ks], Ol[it]);
#pragma unroll
          for (int dt = 0; dt < 4; ++dt)
            O[dt][it] = MFMA16(av[ks][dt], bp[ks], O[dt][it]);
        }
      }
    }
  }

#pragma unroll
  for (int it = 0; it < 4; ++it) {
    float inv = 1.0f / (Ol[it][0] - nm);  // remove masked keys' exp2(0)=1
    int tq = qt * 256 + wave * 64 + it * 16 + c;
    size_t rb = ((size_t)bidx * 2048 + tq) * 1024 + (size_t)(bh & 15) * 64;
#pragma unroll
    for (int dt = 0; dt < 4; ++dt) {
      short4v ov;
#pragma unroll
      for (int r = 0; r < 4; ++r) ov[r] = f2bf(O[dt][it][r] * inv);
      *(short4v*)&Og[rb + dt * 16 + quad * 4] = ov;
    }
  }
}

// ---------------------------------------------------------------------------
// Kernel 4: output projection GEMM: out = attout @ Wo^T + bo (fp32 out).
//   64x128 tile, BK=32, double-buffered staging -> 1024 blocks, 24 KB LDS.
// ---------------------------------------------------------------------------
__global__ __launch_bounds__(256) void out_gemm(
    const short* __restrict__ Ab, const short* __restrict__ Wob,
    const float* __restrict__ bo, float* __restrict__ out) {
  __shared__ __align__(16) short As[2][64 * 32];   // 8 KB
  __shared__ __align__(16) short Bs[2][128 * 32];  // 16 KB

  const int t = threadIdx.x;
  const int lane = t & 63;
  const int wave = t >> 6;
  const int c = lane & 15;
  const int quad = lane >> 4;
  const int m0 = blockIdx.x * 64;
  const int n0 = blockIdx.y * 128;

  f32x4 zero4 = {0.f, 0.f, 0.f, 0.f};
  f32x4 acc[4][2];
#pragma unroll
  for (int i = 0; i < 4; ++i) {
    acc[i][0] = zero4;
    acc[i][1] = zero4;
  }

  const int srow = t >> 2;
  const int gc = ((t & 3) - (srow >> 2)) & 3;
  const short* gA = Ab + (size_t)(m0 + srow) * 1024 + gc * 8;
  const short* gB = Wob + (size_t)(n0 + srow) * 1024 + gc * 8;

#define OUT_STAGE(buf, k0)                                   \
  do {                                                       \
    gld_lds16(gA + (k0), &As[buf][t * 8]);                   \
    gld_lds16(gB + (k0), &Bs[buf][t * 8]);                   \
    gld_lds16(gB + (k0) + 65536, &Bs[buf][t * 8 + 2048]);    \
  } while (0)

  OUT_STAGE(0, 0);

  for (int ki = 0; ki < 32; ++ki) {
    __syncthreads();
    if (ki < 31) OUT_STAGE((ki + 1) & 1, (ki + 1) * 32);

    const short* as = &As[ki & 1][0];
    const short* bs = &Bs[ki & 1][0];
    bf16x8 af[4], bfr[2];
#pragma unroll
    for (int i = 0; i < 4; ++i) {
      int mr = i * 16 + c;
      af[i] = *(const bf16x8*)&as[mr * 32 + (((quad + (mr >> 2)) & 3) * 8)];
    }
#pragma unroll
    for (int j = 0; j < 2; ++j) {
      int nr = wave * 32 + j * 16 + c;
      bfr[j] = *(const bf16x8*)&bs[nr * 32 + (((quad + (nr >> 2)) & 3) * 8)];
    }
#pragma unroll
    for (int i = 0; i < 4; ++i) {
      acc[i][0] = MFMA16(af[i], bfr[0], acc[i][0]);
      acc[i][1] = MFMA16(af[i], bfr[1], acc[i][1]);
    }
  }
#undef OUT_STAGE

  const int nb = n0 + wave * 32;
  float bj[2];
  bj[0] = bo[nb + c];
  bj[1] = bo[nb + 16 + c];
#pragma unroll
  for (int i = 0; i < 4; ++i) {
    int m = m0 + i * 16 + quad * 4;
#pragma unroll
    for (int r = 0; r < 4; ++r) {
      float* orow = out + (size_t)(m + r) * 1024 + nb;
      orow[c]      = acc[i][0][r] + bj[0];
      orow[16 + c] = acc[i][1][r] + bj[1];
    }
  }
}

// ---------------------------------------------------------------------------
extern "C" void kernel_launch(void* const* d_in, const int* in_sizes, int n_in,
                              void* d_out, int out_size, void* d_ws,
                              size_t ws_size, hipStream_t stream) {
  const float* x    = (const float*)d_in[0];
  const float* rope = (const float*)d_in[1];
  const int*   mask = (const int*)d_in[2];
  const float* Wq   = (const float*)d_in[3];
  const float* bq   = (const float*)d_in[4];
  const float* Wk   = (const float*)d_in[5];
  const float* bk   = (const float*)d_in[6];
  const float* Wv   = (const float*)d_in[7];
  const float* bv   = (const float*)d_in[8];
  const float* Wo   = (const float*)d_in[9];
  const float* bo   = (const float*)d_in[10];
  float* out = (float*)d_out;

  char* ws = (char*)d_ws;
  short* xb  = (short*)(ws);               // 16 MB; reused as attout later
  short* wqb = (short*)(ws + 16777216);    // 2 MB each
  short* wkb = (short*)(ws + 18874368);
  short* wvb = (short*)(ws + 20971520);
  short* wob = (short*)(ws + 23068672);
  short* Qh  = (short*)(ws + 25198592);    // 16 MB  [bh][t][64]
  short* Kh  = (short*)(ws + 41975808);    // 16 MB  [bh][t][64]
  short* Vt  = (short*)(ws + 58753024);    // 16 MB  [bh][64][t]
  short* att = xb;  // safe: xb consumed by qkv3_gemm before attn writes

  cvt_kernel<<<12288, 256, 0, stream>>>(x, Wq, Wk, Wv, Wo, xb, wqb, wkb, wvb,
                                        wob);
  qkv3_gemm<<<dim3(64, 8), 256, 0, stream>>>(xb, wqb, wkb, wvb, bq, bk, bv,
                                             rope, mask, Qh, Kh, Vt);
  attn_kernel<<<dim3(64, 8), 256, 0, stream>>>(Qh, Kh, Vt, mask, att);
  out_gemm<<<dim3(128, 8), 256, 0, stream>>>(att, wob, bo, out);
}

// Round 7
// 322.415 us; speedup vs baseline: 1.2771x; 1.2771x over previous
//
#include <hip/hip_runtime.h>
#include <stdint.h>

// B=4, T=2048, C=1024, H=16, D=64, R=32
// Pipeline: cvt -> qkv3_gemm(fused QKV, dbuf) -> attn(hybrid: K LDS-staged,
//   V direct-from-L2, in-register P) -> out_gemm(dbuf)

typedef __attribute__((ext_vector_type(8))) short bf16x8;   // 8 bf16 (4 VGPRs)
typedef __attribute__((ext_vector_type(4))) float f32x4;    // MFMA accumulator
typedef __attribute__((ext_vector_type(4))) short short4v;  // 8-byte packed load/store

#define MFMA16(a, b, c) __builtin_amdgcn_mfma_f32_16x16x32_bf16((a), (b), (c), 0, 0, 0)

#if __has_builtin(__builtin_amdgcn_exp2f)
#define FEXP(x) __builtin_amdgcn_exp2f(x)
#define QSCALE 0.18033688011112042f  // 0.125 * log2(e)
#else
#define FEXP(x) __expf(x)
#define QSCALE 0.125f
#endif

static __device__ __forceinline__ short f2bf(float f) {
  union { float fv; uint32_t u; } v; v.fv = f;
  uint32_t r = v.u + 0x7FFFu + ((v.u >> 16) & 1u);  // RNE
  return (short)(r >> 16);
}

// pack two fp32 -> two bf16 (truncation) in one v_perm_b32
static __device__ __forceinline__ uint32_t pack_trunc(float a, float b) {
  union { float f; uint32_t u; } ua, ub;
  ua.f = a; ub.f = b;
#if __has_builtin(__builtin_amdgcn_perm)
  return __builtin_amdgcn_perm(ub.u, ua.u, 0x07060302u);
#else
  return (ub.u & 0xFFFF0000u) | (ua.u >> 16);
#endif
}

typedef __attribute__((address_space(1))) void as1_void;
typedef __attribute__((address_space(3))) void as3_void;
static __device__ __forceinline__ void gld_lds16(const void* g, void* l) {
  __builtin_amdgcn_global_load_lds((as1_void*)g, (as3_void*)l, 16, 0, 0);
}

// ---------------------------------------------------------------------------
// Kernel 1: fp32 -> bf16 conversion for x, Wq, Wk, Wv, Wo
// ---------------------------------------------------------------------------
__global__ __launch_bounds__(256) void cvt_kernel(
    const float* x, const float* wq, const float* wk, const float* wv,
    const float* wo,
    short* xb, short* wqb, short* wkb, short* wvb, short* wob) {
  int64_t g = (int64_t)blockIdx.x * 256 + threadIdx.x;  // unit = 4 floats
  const int64_t NX = 8388608 / 4, NW = 1048576 / 4;
  const float* src;
  short* dst;
  int64_t i;
  if (g < NX)               { src = x;  dst = xb;  i = g; }
  else if (g < NX + NW)     { src = wq; dst = wqb; i = g - NX; }
  else if (g < NX + 2 * NW) { src = wk; dst = wkb; i = g - NX - NW; }
  else if (g < NX + 3 * NW) { src = wv; dst = wvb; i = g - NX - 2 * NW; }
  else                      { src = wo; dst = wob; i = g - NX - 3 * NW; }
  float4 v = ((const float4*)src)[i];
  short4v o;
  o[0] = f2bf(v.x); o[1] = f2bf(v.y); o[2] = f2bf(v.z); o[3] = f2bf(v.w);
  *(short4v*)&dst[i * 4] = o;
}

// ---------------------------------------------------------------------------
// Kernel 2: fused QKV projection (M=8192, N=1024 x3, K=1024), BK=32.
//   One A-tile stage feeds 3 B-tiles: 48 MFMA per barrier. Double-buffered
//   staging issued right after the barrier.
//   Q: scaled by QSCALE; K,V: masked rows zeroed.
//   Q,K written [bh][t][64] bf16; V written [bh][64][t] bf16 (transposed).
// ---------------------------------------------------------------------------
__global__ __launch_bounds__(256, 2) void qkv3_gemm(
    const short* __restrict__ Xb,
    const short* __restrict__ Wq, const short* __restrict__ Wk,
    const short* __restrict__ Wv,
    const float* __restrict__ bq, const float* __restrict__ bk,
    const float* __restrict__ bv,
    const float* __restrict__ rope, const int* __restrict__ mask,
    short* __restrict__ Qh, short* __restrict__ Kh, short* __restrict__ Vt) {
  __shared__ __align__(16) short As[2][128 * 32];     // 16 KB
  __shared__ __align__(16) short Bs[2][3][128 * 32];  // 48 KB

  const int t = threadIdx.x;
  const int lane = t & 63;
  const int wave = t >> 6;
  const int c = lane & 15;
  const int quad = lane >> 4;
  const int m0 = blockIdx.x * 128;
  const int n0 = blockIdx.y * 128;

  f32x4 zero4 = {0.f, 0.f, 0.f, 0.f};
  f32x4 acc[3][4][4];
#pragma unroll
  for (int m = 0; m < 3; ++m)
#pragma unroll
    for (int i = 0; i < 4; ++i)
#pragma unroll
      for (int j = 0; j < 4; ++j) acc[m][i][j] = zero4;

  const int wm = wave & 1, wn = wave >> 1;

  const int srow = t >> 2;
  const int gc = ((t & 3) - (srow >> 2)) & 3;
  const short* gA = Xb + (size_t)(m0 + srow) * 1024 + gc * 8;
  const short* gW0 = Wq + (size_t)(n0 + srow) * 1024 + gc * 8;
  const short* gW1 = Wk + (size_t)(n0 + srow) * 1024 + gc * 8;
  const short* gW2 = Wv + (size_t)(n0 + srow) * 1024 + gc * 8;

#define QKV_STAGE(buf, k0)                                  \
  do {                                                      \
    gld_lds16(gA + (k0), &As[buf][t * 8]);                  \
    gld_lds16(gA + (k0) + 65536, &As[buf][t * 8 + 2048]);   \
    gld_lds16(gW0 + (k0), &Bs[buf][0][t * 8]);              \
    gld_lds16(gW0 + (k0) + 65536, &Bs[buf][0][t * 8 + 2048]); \
    gld_lds16(gW1 + (k0), &Bs[buf][1][t * 8]);              \
    gld_lds16(gW1 + (k0) + 65536, &Bs[buf][1][t * 8 + 2048]); \
    gld_lds16(gW2 + (k0), &Bs[buf][2][t * 8]);              \
    gld_lds16(gW2 + (k0) + 65536, &Bs[buf][2][t * 8 + 2048]); \
  } while (0)

  QKV_STAGE(0, 0);

  for (int ki = 0; ki < 32; ++ki) {
    __syncthreads();  // drains buf[ki&1] loads (issued one compute phase ago)
    if (ki < 31) QKV_STAGE((ki + 1) & 1, (ki + 1) * 32);

    const short* as = &As[ki & 1][0];
    bf16x8 af[4];
#pragma unroll
    for (int i = 0; i < 4; ++i) {
      int mr = wm * 64 + i * 16 + c;
      af[i] = *(const bf16x8*)&as[mr * 32 + (((quad + (mr >> 2)) & 3) * 8)];
    }
#pragma unroll
    for (int m = 0; m < 3; ++m) {
      const short* bs = &Bs[ki & 1][m][0];
      bf16x8 bfr[4];
#pragma unroll
      for (int j = 0; j < 4; ++j) {
        int nr = wn * 64 + j * 16 + c;
        bfr[j] = *(const bf16x8*)&bs[nr * 32 + (((quad + (nr >> 2)) & 3) * 8)];
      }
#pragma unroll
      for (int i = 0; i < 4; ++i)
#pragma unroll
        for (int j = 0; j < 4; ++j)
          acc[m][i][j] = MFMA16(af[i], bfr[j], acc[m][i][j]);
    }
  }
#undef QKV_STAGE

  // ---- epilogue: C/D layout col=lane&15, row=quad*4+reg ----
  const int nb = n0 + wn * 64;  // wave's 64 cols == one head
  const int hcol = nb >> 6;
  const int bidx = m0 >> 11;
  const int tbase = (m0 & 2047) + wm * 64 + quad * 4;
  const int* mrow = mask + bidx * 2048;

  // Q (mat 0) and K (mat 1): [bh][t][64] with RoPE
#pragma unroll
  for (int mat = 0; mat < 2; ++mat) {
    short* Og = (mat == 0) ? Qh : Kh;
    const float* bias = (mat == 0) ? bq : bk;
    float bj[4];
#pragma unroll
    for (int j = 0; j < 4; ++j) bj[j] = bias[nb + j * 16 + c];
    size_t hb = (size_t)(bidx * 16 + hcol) * 2048;
#pragma unroll
    for (int i = 0; i < 4; ++i) {
#pragma unroll
      for (int r = 0; r < 4; ++r) {
        int tp = tbase + i * 16 + r;
        float f = (mat == 0) ? QSCALE : (mrow[tp] ? 1.0f : 0.0f);
        float cosv = rope[tp * 32 + c];
        float sinv = rope[65536 + tp * 32 + c];
        float v0 = acc[mat][i][0][r] + bj[0];
        float v1 = acc[mat][i][1][r] + bj[1];
        float v2 = acc[mat][i][2][r] + bj[2];
        float v3 = acc[mat][i][3][r] + bj[3];
        size_t base = (hb + tp) * 64;
        Og[base + c]      = f2bf((v0 * cosv - v1 * sinv) * f);
        Og[base + 16 + c] = f2bf((v1 * cosv + v0 * sinv) * f);
        Og[base + 32 + c] = f2bf(v2 * f);
        Og[base + 48 + c] = f2bf(v3 * f);
      }
    }
  }
  // V (mat 2): transposed [bh][d][t], masked t zeroed
  {
    float bj[4];
#pragma unroll
    for (int j = 0; j < 4; ++j) bj[j] = bv[nb + j * 16 + c];
    size_t hb = (size_t)(bidx * 16 + hcol) * 64;
#pragma unroll
    for (int i = 0; i < 4; ++i) {
      int tp = tbase + i * 16;  // multiple of 4
      int4 mv = *(const int4*)&mrow[tp];
      float fr[4];
      fr[0] = mv.x ? 1.f : 0.f; fr[1] = mv.y ? 1.f : 0.f;
      fr[2] = mv.z ? 1.f : 0.f; fr[3] = mv.w ? 1.f : 0.f;
#pragma unroll
      for (int j = 0; j < 4; ++j) {
        short4v pv;
#pragma unroll
        for (int r = 0; r < 4; ++r)
          pv[r] = f2bf((acc[2][i][j][r] + bj[j]) * fr[r]);
        size_t base = (hb + j * 16 + c) * 2048 + tp;
        *(short4v*)&Vt[base] = pv;
      }
    }
  }
}

// ---------------------------------------------------------------------------
// Kernel 3: attention, static softmax, HYBRID (round-7).
//   Round-5 (best attn, 76.5us) was LDS-BW-bound: 160 KB/chunk/CU of LDS
//   traffic. Round-6 (zero-LDS) proved the direct-from-L2 fragment addressing
//   correct but spilled (K register dbuf + O-state > VGPR file): 203 MB
//   scratch writes. Hybrid: K stays LDS-staged + double-buffered (zero extra
//   registers vs r5), V fragments load DIRECTLY from L2 just-in-time (av is
//   a transient 32-VGPR block in r5 anyway; the k-slot permutation makes its
//   global addresses contiguous 8B pairs, no swizzle). LDS traffic/chunk/CU:
//   160 KB -> 80 KB (staging 32->16, frag reads 128->64); V's 64 KB moves to
//   the ~9%-utilized L2 pipe. V loads issue at chunk top, first use after
//   QK^T+exp (~600 cyc) >> L2 latency.
//   In-register P via k-slot assignment k_phys(ks,quad,j) (r5, verified).
//   4 waves x 64 q-rows; grid (64 heads, 8 qt); bh-major = head per XCD.
// ---------------------------------------------------------------------------
__global__ __launch_bounds__(256, 2) void attn_kernel(
    const short* __restrict__ Qh, const short* __restrict__ Kh,
    const short* __restrict__ Vt, const int* __restrict__ mask,
    short* __restrict__ Og) {
  __shared__ __align__(16) short Ks[2][64 * 64];  // 16 KB (K only)

  const int t = threadIdx.x;
  const int lane = t & 63;
  const int wave = t >> 6;  // 0..3
  const int c = lane & 15;
  const int quad = lane >> 4;
  const int bh = blockIdx.x;   // 0..63 (x-major: head -> fixed XCD)
  const int qt = blockIdx.y;   // 0..7 (256 q rows each)
  const int bidx = bh >> 4;
  const short* Qg = Qh + ((size_t)bh * 2048 + qt * 256) * 64;
  const short* Kg = Kh + (size_t)bh * 2048 * 64;
  const short* Vg = Vt + (size_t)bh * 64 * 2048;

  // count masked keys for this batch; full butterfly so every lane holds the
  // total (in-register)
  float nm;
  {
    const int4* mr = (const int4*)(mask + bidx * 2048);
    int cnt = 0;
#pragma unroll
    for (int k = 0; k < 8; ++k) {
      int4 a = mr[k * 64 + lane];
      cnt += (a.x == 0) + (a.y == 0) + (a.z == 0) + (a.w == 0);
    }
    cnt += __shfl_xor(cnt, 1);  cnt += __shfl_xor(cnt, 2);
    cnt += __shfl_xor(cnt, 4);  cnt += __shfl_xor(cnt, 8);
    cnt += __shfl_xor(cnt, 16); cnt += __shfl_xor(cnt, 32);
    nm = (float)cnt;
  }

  // Q fragments (B-operand), loop-invariant; wave covers 64 q rows (it 0..3)
  bf16x8 qf[2][4];
#pragma unroll
  for (int ks = 0; ks < 2; ++ks)
#pragma unroll
    for (int it = 0; it < 4; ++it)
      qf[ks][it] =
          *(const bf16x8*)&Qg[(wave * 64 + it * 16 + c) * 64 + ks * 32 + quad * 8];

  const bf16x8 ones = {0x3F80, 0x3F80, 0x3F80, 0x3F80,
                       0x3F80, 0x3F80, 0x3F80, 0x3F80};  // bf16 1.0 x8

  f32x4 zero4 = {0.f, 0.f, 0.f, 0.f};
  f32x4 O[4][4];
#pragma unroll
  for (int dt = 0; dt < 4; ++dt)
#pragma unroll
    for (int it = 0; it < 4; ++it) O[dt][it] = zero4;
  f32x4 Ol[4] = {zero4, zero4, zero4, zero4};

  // K staging: 256 threads x 2 x 16B = 64x64 K tile per chunk
  const int krow0 = t >> 3;                 // 0..31
  const int klc = (t & 7) ^ (krow0 & 7);    // XOR-swizzled 16B col block
  const short* gk0 = Kg + (size_t)krow0 * 64 + klc * 8;

  // prologue: stage chunk 0 into buffer 0
  gld_lds16(gk0, &Ks[0][t * 8]);
  gld_lds16(gk0 + 32 * 64, &Ks[0][t * 8 + 2048]);

  for (int ci = 0; ci < 32; ++ci) {
    __syncthreads();  // drains chunk-ci K loads (issued one compute-phase ago)
    if (ci < 31) {
      int cn = (ci + 1) * 64;
      int nb = (ci + 1) & 1;
      gld_lds16(gk0 + (size_t)cn * 64, &Ks[nb][t * 8]);
      gld_lds16(gk0 + (size_t)(cn + 32) * 64, &Ks[nb][t * 8 + 2048]);
    }
    const short* ksb = &Ks[ci & 1][0];

    // V fragments direct from L2 (JIT; first use after QK^T+exp).
    // Slot j of av[ks][dt] = V^T[dt*16+c][k_phys]:
    // lo (j=0..3): ks*32+quad*4+{0..3}; hi (j=4..7): +16. Contiguous 8B each.
    const short* vc = Vg + ci * 64;  // uniform term
    bf16x8 av[2][4];
#pragma unroll
    for (int ks = 0; ks < 2; ++ks)
#pragma unroll
      for (int dt = 0; dt < 4; ++dt) {
        union { short4v h[2]; bf16x8 v; } uu;
        uu.h[0] = *(const short4v*)&vc[(dt * 16 + c) * 2048 +
                                       ks * 32 + quad * 4];
        uu.h[1] = *(const short4v*)&vc[(dt * 16 + c) * 2048 +
                                       ks * 32 + 16 + quad * 4];
        av[ks][dt] = uu.v;
      }

    // hoisted K fragments (A-operand of S^T), contiguous 16B swizzled blocks
    bf16x8 ak[2][4];
#pragma unroll
    for (int ks = 0; ks < 2; ++ks)
#pragma unroll
      for (int jt = 0; jt < 4; ++jt)
        ak[ks][jt] = *(const bf16x8*)&ksb[(jt * 16 + c) * 64 +
                                          (((4 * ks + quad) ^ (c & 7)) * 8)];

#pragma unroll
    for (int it = 0; it < 4; ++it) {  // four 16-row q sub-blocks
      f32x4 St[4];
#pragma unroll
      for (int jt = 0; jt < 4; ++jt)
        St[jt] = MFMA16(ak[0][jt], qf[0][it], zero4);
#pragma unroll
      for (int jt = 0; jt < 4; ++jt)
        St[jt] = MFMA16(ak[1][jt], qf[1][it], St[jt]);

      // exp2 + pack -> PV B-fragments, entirely in-register.
      bf16x8 bp[2];
#pragma unroll
      for (int ks = 0; ks < 2; ++ks) {
        union { uint32_t w[4]; bf16x8 v; } uu;
        uu.w[0] = pack_trunc(FEXP(St[2 * ks][0]),     FEXP(St[2 * ks][1]));
        uu.w[1] = pack_trunc(FEXP(St[2 * ks][2]),     FEXP(St[2 * ks][3]));
        uu.w[2] = pack_trunc(FEXP(St[2 * ks + 1][0]), FEXP(St[2 * ks + 1][1]));
        uu.w[3] = pack_trunc(FEXP(St[2 * ks + 1][2]), FEXP(St[2 * ks + 1][3]));
        bp[ks] = uu.v;
      }

#pragma unroll
      for (int ks = 0; ks < 2; ++ks) {
        Ol[it] = MFMA16(ones, bp[ks], Ol[it]);
#pragma unroll
        for (int dt = 0; dt < 4; ++dt)
          O[dt][it] = MFMA16(av[ks][dt], bp[ks], O[dt][it]);
      }
    }
  }

#pragma unroll
  for (int it = 0; it < 4; ++it) {
    float inv = 1.0f / (Ol[it][0] - nm);  // remove masked keys' exp2(0)=1
    int tq = qt * 256 + wave * 64 + it * 16 + c;
    size_t rb = ((size_t)bidx * 2048 + tq) * 1024 + (size_t)(bh & 15) * 64;
#pragma unroll
    for (int dt = 0; dt < 4; ++dt) {
      short4v ov;
#pragma unroll
      for (int r = 0; r < 4; ++r) ov[r] = f2bf(O[dt][it][r] * inv);
      *(short4v*)&Og[rb + dt * 16 + quad * 4] = ov;
    }
  }
}

// ---------------------------------------------------------------------------
// Kernel 4: output projection GEMM: out = attout @ Wo^T + bo (fp32 out).
//   64x128 tile, BK=32, double-buffered staging -> 1024 blocks, 24 KB LDS.
// ---------------------------------------------------------------------------
__global__ __launch_bounds__(256) void out_gemm(
    const short* __restrict__ Ab, const short* __restrict__ Wob,
    const float* __restrict__ bo, float* __restrict__ out) {
  __shared__ __align__(16) short As[2][64 * 32];   // 8 KB
  __shared__ __align__(16) short Bs[2][128 * 32];  // 16 KB

  const int t = threadIdx.x;
  const int lane = t & 63;
  const int wave = t >> 6;
  const int c = lane & 15;
  const int quad = lane >> 4;
  const int m0 = blockIdx.x * 64;
  const int n0 = blockIdx.y * 128;

  f32x4 zero4 = {0.f, 0.f, 0.f, 0.f};
  f32x4 acc[4][2];
#pragma unroll
  for (int i = 0; i < 4; ++i) {
    acc[i][0] = zero4;
    acc[i][1] = zero4;
  }

  const int srow = t >> 2;
  const int gc = ((t & 3) - (srow >> 2)) & 3;
  const short* gA = Ab + (size_t)(m0 + srow) * 1024 + gc * 8;
  const short* gB = Wob + (size_t)(n0 + srow) * 1024 + gc * 8;

#define OUT_STAGE(buf, k0)                                   \
  do {                                                       \
    gld_lds16(gA + (k0), &As[buf][t * 8]);                   \
    gld_lds16(gB + (k0), &Bs[buf][t * 8]);                   \
    gld_lds16(gB + (k0) + 65536, &Bs[buf][t * 8 + 2048]);    \
  } while (0)

  OUT_STAGE(0, 0);

  for (int ki = 0; ki < 32; ++ki) {
    __syncthreads();
    if (ki < 31) OUT_STAGE((ki + 1) & 1, (ki + 1) * 32);

    const short* as = &As[ki & 1][0];
    const short* bs = &Bs[ki & 1][0];
    bf16x8 af[4], bfr[2];
#pragma unroll
    for (int i = 0; i < 4; ++i) {
      int mr = i * 16 + c;
      af[i] = *(const bf16x8*)&as[mr * 32 + (((quad + (mr >> 2)) & 3) * 8)];
    }
#pragma unroll
    for (int j = 0; j < 2; ++j) {
      int nr = wave * 32 + j * 16 + c;
      bfr[j] = *(const bf16x8*)&bs[nr * 32 + (((quad + (nr >> 2)) & 3) * 8)];
    }
#pragma unroll
    for (int i = 0; i < 4; ++i) {
      acc[i][0] = MFMA16(af[i], bfr[0], acc[i][0]);
      acc[i][1] = MFMA16(af[i], bfr[1], acc[i][1]);
    }
  }
#undef OUT_STAGE

  const int nb = n0 + wave * 32;
  float bj[2];
  bj[0] = bo[nb + c];
  bj[1] = bo[nb + 16 + c];
#pragma unroll
  for (int i = 0; i < 4; ++i) {
    int m = m0 + i * 16 + quad * 4;
#pragma unroll
    for (int r = 0; r < 4; ++r) {
      float* orow = out + (size_t)(m + r) * 1024 + nb;
      orow[c]      = acc[i][0][r] + bj[0];
      orow[16 + c] = acc[i][1][r] + bj[1];
    }
  }
}

// ---------------------------------------------------------------------------
extern "C" void kernel_launch(void* const* d_in, const int* in_sizes, int n_in,
                              void* d_out, int out_size, void* d_ws,
                              size_t ws_size, hipStream_t stream) {
  const float* x    = (const float*)d_in[0];
  const float* rope = (const float*)d_in[1];
  const int*   mask = (const int*)d_in[2];
  const float* Wq   = (const float*)d_in[3];
  const float* bq   = (const float*)d_in[4];
  const float* Wk   = (const float*)d_in[5];
  const float* bk   = (const float*)d_in[6];
  const float* Wv   = (const float*)d_in[7];
  const float* bv   = (const float*)d_in[8];
  const float* Wo   = (const float*)d_in[9];
  const float* bo   = (const float*)d_in[10];
  float* out = (float*)d_out;

  char* ws = (char*)d_ws;
  short* xb  = (short*)(ws);               // 16 MB; reused as attout later
  short* wqb = (short*)(ws + 16777216);    // 2 MB each
  short* wkb = (short*)(ws + 18874368);
  short* wvb = (short*)(ws + 20971520);
  short* wob = (short*)(ws + 23068672);
  short* Qh  = (short*)(ws + 25198592);    // 16 MB  [bh][t][64]
  short* Kh  = (short*)(ws + 41975808);    // 16 MB  [bh][t][64]
  short* Vt  = (short*)(ws + 58753024);    // 16 MB  [bh][64][t]
  short* att = xb;  // safe: xb consumed by qkv3_gemm before attn writes

  cvt_kernel<<<12288, 256, 0, stream>>>(x, Wq, Wk, Wv, Wo, xb, wqb, wkb, wvb,
                                        wob);
  qkv3_gemm<<<dim3(64, 8), 256, 0, stream>>>(xb, wqb, wkb, wvb, bq, bk, bv,
                                             rope, mask, Qh, Kh, Vt);
  attn_kernel<<<dim3(64, 8), 256, 0, stream>>>(Qh, Kh, Vt, mask, att);
  out_gemm<<<dim3(128, 8), 256, 0, stream>>>(att, wob, bo, out);
}

// Round 8
// 263.631 us; speedup vs baseline: 1.5618x; 1.2230x over previous
//
#include <hip/hip_runtime.h>
#include <stdint.h>

// B=4, T=2048, C=1024, H=16, D=64, R=32
// Pipeline: cvt -> qkv3_gemm(fused QKV, dbuf) -> attn(r5: K/V LDS-staged,
//   in-register P) -> out_gemm(128x128 tile, dbuf)

typedef __attribute__((ext_vector_type(8))) short bf16x8;   // 8 bf16 (4 VGPRs)
typedef __attribute__((ext_vector_type(4))) float f32x4;    // MFMA accumulator
typedef __attribute__((ext_vector_type(4))) short short4v;  // 8-byte packed load/store

#define MFMA16(a, b, c) __builtin_amdgcn_mfma_f32_16x16x32_bf16((a), (b), (c), 0, 0, 0)

#if __has_builtin(__builtin_amdgcn_exp2f)
#define FEXP(x) __builtin_amdgcn_exp2f(x)
#define QSCALE 0.18033688011112042f  // 0.125 * log2(e)
#else
#define FEXP(x) __expf(x)
#define QSCALE 0.125f
#endif

static __device__ __forceinline__ short f2bf(float f) {
  union { float fv; uint32_t u; } v; v.fv = f;
  uint32_t r = v.u + 0x7FFFu + ((v.u >> 16) & 1u);  // RNE
  return (short)(r >> 16);
}

// pack two fp32 -> two bf16 (truncation) in one v_perm_b32
static __device__ __forceinline__ uint32_t pack_trunc(float a, float b) {
  union { float f; uint32_t u; } ua, ub;
  ua.f = a; ub.f = b;
#if __has_builtin(__builtin_amdgcn_perm)
  return __builtin_amdgcn_perm(ub.u, ua.u, 0x07060302u);
#else
  return (ub.u & 0xFFFF0000u) | (ua.u >> 16);
#endif
}

typedef __attribute__((address_space(1))) void as1_void;
typedef __attribute__((address_space(3))) void as3_void;
static __device__ __forceinline__ void gld_lds16(const void* g, void* l) {
  __builtin_amdgcn_global_load_lds((as1_void*)g, (as3_void*)l, 16, 0, 0);
}

// ---------------------------------------------------------------------------
// Kernel 1: fp32 -> bf16 conversion for x, Wq, Wk, Wv, Wo
// ---------------------------------------------------------------------------
__global__ __launch_bounds__(256) void cvt_kernel(
    const float* x, const float* wq, const float* wk, const float* wv,
    const float* wo,
    short* xb, short* wqb, short* wkb, short* wvb, short* wob) {
  int64_t g = (int64_t)blockIdx.x * 256 + threadIdx.x;  // unit = 4 floats
  const int64_t NX = 8388608 / 4, NW = 1048576 / 4;
  const float* src;
  short* dst;
  int64_t i;
  if (g < NX)               { src = x;  dst = xb;  i = g; }
  else if (g < NX + NW)     { src = wq; dst = wqb; i = g - NX; }
  else if (g < NX + 2 * NW) { src = wk; dst = wkb; i = g - NX - NW; }
  else if (g < NX + 3 * NW) { src = wv; dst = wvb; i = g - NX - 2 * NW; }
  else                      { src = wo; dst = wob; i = g - NX - 3 * NW; }
  float4 v = ((const float4*)src)[i];
  short4v o;
  o[0] = f2bf(v.x); o[1] = f2bf(v.y); o[2] = f2bf(v.z); o[3] = f2bf(v.w);
  *(short4v*)&dst[i * 4] = o;
}

// ---------------------------------------------------------------------------
// Kernel 2: fused QKV projection (M=8192, N=1024 x3, K=1024), BK=32.
//   One A-tile stage feeds 3 B-tiles: 48 MFMA per barrier. Double-buffered
//   staging issued right after the barrier.
//   Q: scaled by QSCALE; K,V: masked rows zeroed.
//   Q,K written [bh][t][64] bf16; V written [bh][64][t] bf16 (transposed).
// ---------------------------------------------------------------------------
__global__ __launch_bounds__(256, 2) void qkv3_gemm(
    const short* __restrict__ Xb,
    const short* __restrict__ Wq, const short* __restrict__ Wk,
    const short* __restrict__ Wv,
    const float* __restrict__ bq, const float* __restrict__ bk,
    const float* __restrict__ bv,
    const float* __restrict__ rope, const int* __restrict__ mask,
    short* __restrict__ Qh, short* __restrict__ Kh, short* __restrict__ Vt) {
  __shared__ __align__(16) short As[2][128 * 32];     // 16 KB
  __shared__ __align__(16) short Bs[2][3][128 * 32];  // 48 KB

  const int t = threadIdx.x;
  const int lane = t & 63;
  const int wave = t >> 6;
  const int c = lane & 15;
  const int quad = lane >> 4;
  const int m0 = blockIdx.x * 128;
  const int n0 = blockIdx.y * 128;

  f32x4 zero4 = {0.f, 0.f, 0.f, 0.f};
  f32x4 acc[3][4][4];
#pragma unroll
  for (int m = 0; m < 3; ++m)
#pragma unroll
    for (int i = 0; i < 4; ++i)
#pragma unroll
      for (int j = 0; j < 4; ++j) acc[m][i][j] = zero4;

  const int wm = wave & 1, wn = wave >> 1;

  const int srow = t >> 2;
  const int gc = ((t & 3) - (srow >> 2)) & 3;
  const short* gA = Xb + (size_t)(m0 + srow) * 1024 + gc * 8;
  const short* gW0 = Wq + (size_t)(n0 + srow) * 1024 + gc * 8;
  const short* gW1 = Wk + (size_t)(n0 + srow) * 1024 + gc * 8;
  const short* gW2 = Wv + (size_t)(n0 + srow) * 1024 + gc * 8;

#define QKV_STAGE(buf, k0)                                  \
  do {                                                      \
    gld_lds16(gA + (k0), &As[buf][t * 8]);                  \
    gld_lds16(gA + (k0) + 65536, &As[buf][t * 8 + 2048]);   \
    gld_lds16(gW0 + (k0), &Bs[buf][0][t * 8]);              \
    gld_lds16(gW0 + (k0) + 65536, &Bs[buf][0][t * 8 + 2048]); \
    gld_lds16(gW1 + (k0), &Bs[buf][1][t * 8]);              \
    gld_lds16(gW1 + (k0) + 65536, &Bs[buf][1][t * 8 + 2048]); \
    gld_lds16(gW2 + (k0), &Bs[buf][2][t * 8]);              \
    gld_lds16(gW2 + (k0) + 65536, &Bs[buf][2][t * 8 + 2048]); \
  } while (0)

  QKV_STAGE(0, 0);

  for (int ki = 0; ki < 32; ++ki) {
    __syncthreads();  // drains buf[ki&1] loads (issued one compute phase ago)
    if (ki < 31) QKV_STAGE((ki + 1) & 1, (ki + 1) * 32);

    const short* as = &As[ki & 1][0];
    bf16x8 af[4];
#pragma unroll
    for (int i = 0; i < 4; ++i) {
      int mr = wm * 64 + i * 16 + c;
      af[i] = *(const bf16x8*)&as[mr * 32 + (((quad + (mr >> 2)) & 3) * 8)];
    }
#pragma unroll
    for (int m = 0; m < 3; ++m) {
      const short* bs = &Bs[ki & 1][m][0];
      bf16x8 bfr[4];
#pragma unroll
      for (int j = 0; j < 4; ++j) {
        int nr = wn * 64 + j * 16 + c;
        bfr[j] = *(const bf16x8*)&bs[nr * 32 + (((quad + (nr >> 2)) & 3) * 8)];
      }
#pragma unroll
      for (int i = 0; i < 4; ++i)
#pragma unroll
        for (int j = 0; j < 4; ++j)
          acc[m][i][j] = MFMA16(af[i], bfr[j], acc[m][i][j]);
    }
  }
#undef QKV_STAGE

  // ---- epilogue: C/D layout col=lane&15, row=quad*4+reg ----
  const int nb = n0 + wn * 64;  // wave's 64 cols == one head
  const int hcol = nb >> 6;
  const int bidx = m0 >> 11;
  const int tbase = (m0 & 2047) + wm * 64 + quad * 4;
  const int* mrow = mask + bidx * 2048;

  // Q (mat 0) and K (mat 1): [bh][t][64] with RoPE
#pragma unroll
  for (int mat = 0; mat < 2; ++mat) {
    short* Og = (mat == 0) ? Qh : Kh;
    const float* bias = (mat == 0) ? bq : bk;
    float bj[4];
#pragma unroll
    for (int j = 0; j < 4; ++j) bj[j] = bias[nb + j * 16 + c];
    size_t hb = (size_t)(bidx * 16 + hcol) * 2048;
#pragma unroll
    for (int i = 0; i < 4; ++i) {
#pragma unroll
      for (int r = 0; r < 4; ++r) {
        int tp = tbase + i * 16 + r;
        float f = (mat == 0) ? QSCALE : (mrow[tp] ? 1.0f : 0.0f);
        float cosv = rope[tp * 32 + c];
        float sinv = rope[65536 + tp * 32 + c];
        float v0 = acc[mat][i][0][r] + bj[0];
        float v1 = acc[mat][i][1][r] + bj[1];
        float v2 = acc[mat][i][2][r] + bj[2];
        float v3 = acc[mat][i][3][r] + bj[3];
        size_t base = (hb + tp) * 64;
        Og[base + c]      = f2bf((v0 * cosv - v1 * sinv) * f);
        Og[base + 16 + c] = f2bf((v1 * cosv + v0 * sinv) * f);
        Og[base + 32 + c] = f2bf(v2 * f);
        Og[base + 48 + c] = f2bf(v3 * f);
      }
    }
  }
  // V (mat 2): transposed [bh][d][t], masked t zeroed
  {
    float bj[4];
#pragma unroll
    for (int j = 0; j < 4; ++j) bj[j] = bv[nb + j * 16 + c];
    size_t hb = (size_t)(bidx * 16 + hcol) * 64;
#pragma unroll
    for (int i = 0; i < 4; ++i) {
      int tp = tbase + i * 16;  // multiple of 4
      int4 mv = *(const int4*)&mrow[tp];
      float fr[4];
      fr[0] = mv.x ? 1.f : 0.f; fr[1] = mv.y ? 1.f : 0.f;
      fr[2] = mv.z ? 1.f : 0.f; fr[3] = mv.w ? 1.f : 0.f;
#pragma unroll
      for (int j = 0; j < 4; ++j) {
        short4v pv;
#pragma unroll
        for (int r = 0; r < 4; ++r)
          pv[r] = f2bf((acc[2][i][j][r] + bj[j]) * fr[r]);
        size_t base = (hb + j * 16 + c) * 2048 + tp;
        *(short4v*)&Vt[base] = pv;
      }
    }
  }
}

// ---------------------------------------------------------------------------
// Kernel 3: attention, static softmax, IN-REGISTER P (r5 exact — best
//   measured: 76.5us). K/V LDS-staged double-buffered (r7 proved V must go
//   through coalesced gld_lds: direct-from-L2 V loads scatter 16 segments
//   per instr -> 2x slower). In-register P via k-slot assignment
//   k_phys(ks,quad,j) = (2ks+(j>>2))*16 + quad*4 + (j&3): PV B-fragment is
//   the exp2'd St values the lane already holds; V A-fragment absorbs the
//   permutation as two swizzled 8B LDS reads (same bytes, no extra traffic).
//   4 waves x 64 q-rows; grid (64 heads, 8 qt); bh-major = head per XCD.
// ---------------------------------------------------------------------------
__global__ __launch_bounds__(256, 2) void attn_kernel(
    const short* __restrict__ Qh, const short* __restrict__ Kh,
    const short* __restrict__ Vt, const int* __restrict__ mask,
    short* __restrict__ Og) {
  __shared__ __align__(16) short Ks[2][64 * 64];  // 16 KB
  __shared__ __align__(16) short Vs[2][64 * 64];  // 16 KB

  const int t = threadIdx.x;
  const int lane = t & 63;
  const int wave = t >> 6;  // 0..3
  const int c = lane & 15;
  const int quad = lane >> 4;
  const int bh = blockIdx.x;   // 0..63 (x-major: head -> fixed XCD)
  const int qt = blockIdx.y;   // 0..7 (256 q rows each)
  const int bidx = bh >> 4;
  const short* Qg = Qh + ((size_t)bh * 2048 + qt * 256) * 64;
  const short* Kg = Kh + (size_t)bh * 2048 * 64;
  const short* Vg = Vt + (size_t)bh * 64 * 2048;

  // count masked keys for this batch; full butterfly so every lane holds the
  // total (in-register, no LDS scalar / extra barrier dependence)
  float nm;
  {
    const int4* mr = (const int4*)(mask + bidx * 2048);
    int cnt = 0;
#pragma unroll
    for (int k = 0; k < 8; ++k) {
      int4 a = mr[k * 64 + lane];
      cnt += (a.x == 0) + (a.y == 0) + (a.z == 0) + (a.w == 0);
    }
    cnt += __shfl_xor(cnt, 1);  cnt += __shfl_xor(cnt, 2);
    cnt += __shfl_xor(cnt, 4);  cnt += __shfl_xor(cnt, 8);
    cnt += __shfl_xor(cnt, 16); cnt += __shfl_xor(cnt, 32);
    nm = (float)cnt;
  }

  // Q fragments (B-operand), loop-invariant; wave covers 64 q rows (it 0..3)
  bf16x8 qf[2][4];
#pragma unroll
  for (int ks = 0; ks < 2; ++ks)
#pragma unroll
    for (int it = 0; it < 4; ++it)
      qf[ks][it] =
          *(const bf16x8*)&Qg[(wave * 64 + it * 16 + c) * 64 + ks * 32 + quad * 8];

  const bf16x8 ones = {0x3F80, 0x3F80, 0x3F80, 0x3F80,
                       0x3F80, 0x3F80, 0x3F80, 0x3F80};  // bf16 1.0 x8

  f32x4 zero4 = {0.f, 0.f, 0.f, 0.f};
  f32x4 O[4][4];
#pragma unroll
  for (int dt = 0; dt < 4; ++dt)
#pragma unroll
    for (int it = 0; it < 4; ++it) O[dt][it] = zero4;
  f32x4 Ol[4] = {zero4, zero4, zero4, zero4};

  // staging: 256 threads x 4 x 16B = 64x64 K tile + 64x64 V tile per chunk
  const int krow0 = t >> 3;                 // 0..31
  const int klc = (t & 7) ^ (krow0 & 7);    // XOR-swizzled 16B col block
  const short* gk0 = Kg + (size_t)krow0 * 64 + klc * 8;
  const short* gv0 = Vg + (size_t)krow0 * 2048 + klc * 8;

  // prologue: stage chunk 0 into buffer 0
  gld_lds16(gk0, &Ks[0][t * 8]);
  gld_lds16(gk0 + 32 * 64, &Ks[0][t * 8 + 2048]);
  gld_lds16(gv0, &Vs[0][t * 8]);
  gld_lds16(gv0 + 32 * 2048, &Vs[0][t * 8 + 2048]);

  const int s2 = (c & 7) * 2;  // 8B-unit swizzle for V fragment reads

  for (int ci = 0; ci < 32; ++ci) {
    __syncthreads();  // drains chunk-ci loads (issued one compute-phase ago)
    if (ci < 31) {
      int cn = (ci + 1) * 64;
      int nb = (ci + 1) & 1;
      gld_lds16(gk0 + (size_t)cn * 64, &Ks[nb][t * 8]);
      gld_lds16(gk0 + (size_t)(cn + 32) * 64, &Ks[nb][t * 8 + 2048]);
      gld_lds16(gv0 + cn, &Vs[nb][t * 8]);
      gld_lds16(gv0 + cn + 32 * 2048, &Vs[nb][t * 8 + 2048]);
    }
    const short* ksb = &Ks[ci & 1][0];
    const short* vsb = &Vs[ci & 1][0];

    // hoisted K fragments (A-operand of S^T), contiguous 16B swizzled blocks
    bf16x8 ak[2][4];
#pragma unroll
    for (int ks = 0; ks < 2; ++ks)
#pragma unroll
      for (int jt = 0; jt < 4; ++jt)
        ak[ks][jt] = *(const bf16x8*)&ksb[(jt * 16 + c) * 64 +
                                          (((4 * ks + quad) ^ (c & 7)) * 8)];

    // hoisted V fragments (A-operand of PV) under the k-slot permutation:
    // slot j of av[ks][dt] = V^T[dt*16+c][(2ks+(j>>2))*16 + quad*4 + (j&3)]
    // -> two 8B groups at swizzled units u and u^4.
    bf16x8 av[2][4];
#pragma unroll
    for (int ks = 0; ks < 2; ++ks)
#pragma unroll
      for (int dt = 0; dt < 4; ++dt) {
        int u = (8 * ks + quad) ^ s2;
        int rowb = (dt * 16 + c) * 64;
        short4v lo = *(const short4v*)&vsb[rowb + u * 4];
        short4v hi = *(const short4v*)&vsb[rowb + (u ^ 4) * 4];
        union { short4v h[2]; bf16x8 v; } uu;
        uu.h[0] = lo; uu.h[1] = hi;
        av[ks][dt] = uu.v;
      }

#pragma unroll
    for (int it = 0; it < 4; ++it) {  // four 16-row q sub-blocks
      f32x4 St[4];
#pragma unroll
      for (int jt = 0; jt < 4; ++jt)
        St[jt] = MFMA16(ak[0][jt], qf[0][it], zero4);
#pragma unroll
      for (int jt = 0; jt < 4; ++jt)
        St[jt] = MFMA16(ak[1][jt], qf[1][it], St[jt]);

      // exp2 + pack -> PV B-fragments, entirely in-register.
      bf16x8 bp[2];
#pragma unroll
      for (int ks = 0; ks < 2; ++ks) {
        union { uint32_t w[4]; bf16x8 v; } uu;
        uu.w[0] = pack_trunc(FEXP(St[2 * ks][0]),     FEXP(St[2 * ks][1]));
        uu.w[1] = pack_trunc(FEXP(St[2 * ks][2]),     FEXP(St[2 * ks][3]));
        uu.w[2] = pack_trunc(FEXP(St[2 * ks + 1][0]), FEXP(St[2 * ks + 1][1]));
        uu.w[3] = pack_trunc(FEXP(St[2 * ks + 1][2]), FEXP(St[2 * ks + 1][3]));
        bp[ks] = uu.v;
      }

#pragma unroll
      for (int ks = 0; ks < 2; ++ks) {
        Ol[it] = MFMA16(ones, bp[ks], Ol[it]);
#pragma unroll
        for (int dt = 0; dt < 4; ++dt)
          O[dt][it] = MFMA16(av[ks][dt], bp[ks], O[dt][it]);
      }
    }
  }

#pragma unroll
  for (int it = 0; it < 4; ++it) {
    float inv = 1.0f / (Ol[it][0] - nm);  // remove masked keys' exp2(0)=1
    int tq = qt * 256 + wave * 64 + it * 16 + c;
    size_t rb = ((size_t)bidx * 2048 + tq) * 1024 + (size_t)(bh & 15) * 64;
#pragma unroll
    for (int dt = 0; dt < 4; ++dt) {
      short4v ov;
#pragma unroll
      for (int r = 0; r < 4; ++r) ov[r] = f2bf(O[dt][it][r] * inv);
      *(short4v*)&Og[rb + dt * 16 + quad * 4] = ov;
    }
  }
}

// ---------------------------------------------------------------------------
// Kernel 4: output projection GEMM (round-8 rewrite): 128x128 tile, the
//   qkv3 structure with one B matrix. 16 MFMA per wave per K-step on 8 b128
//   LDS reads (density 2.0 vs old 64x128's 1.3). Grid (64,8)=512 blocks,
//   32 KB LDS, 2 blocks/CU. out = attout @ Wo^T + bo (fp32 out).
// ---------------------------------------------------------------------------
__global__ __launch_bounds__(256, 2) void out_gemm(
    const short* __restrict__ Ab, const short* __restrict__ Wob,
    const float* __restrict__ bo, float* __restrict__ out) {
  __shared__ __align__(16) short As[2][128 * 32];  // 16 KB
  __shared__ __align__(16) short Bs[2][128 * 32];  // 16 KB

  const int t = threadIdx.x;
  const int lane = t & 63;
  const int wave = t >> 6;
  const int c = lane & 15;
  const int quad = lane >> 4;
  const int m0 = blockIdx.x * 128;
  const int n0 = blockIdx.y * 128;

  f32x4 zero4 = {0.f, 0.f, 0.f, 0.f};
  f32x4 acc[4][4];
#pragma unroll
  for (int i = 0; i < 4; ++i)
#pragma unroll
    for (int j = 0; j < 4; ++j) acc[i][j] = zero4;

  const int wm = wave & 1, wn = wave >> 1;

  const int srow = t >> 2;
  const int gc = ((t & 3) - (srow >> 2)) & 3;
  const short* gA = Ab + (size_t)(m0 + srow) * 1024 + gc * 8;
  const short* gB = Wob + (size_t)(n0 + srow) * 1024 + gc * 8;

#define OUT_STAGE(buf, k0)                                 \
  do {                                                     \
    gld_lds16(gA + (k0), &As[buf][t * 8]);                 \
    gld_lds16(gA + (k0) + 65536, &As[buf][t * 8 + 2048]);  \
    gld_lds16(gB + (k0), &Bs[buf][t * 8]);                 \
    gld_lds16(gB + (k0) + 65536, &Bs[buf][t * 8 + 2048]);  \
  } while (0)

  OUT_STAGE(0, 0);

  for (int ki = 0; ki < 32; ++ki) {
    __syncthreads();
    if (ki < 31) OUT_STAGE((ki + 1) & 1, (ki + 1) * 32);

    const short* as = &As[ki & 1][0];
    const short* bs = &Bs[ki & 1][0];
    bf16x8 af[4], bfr[4];
#pragma unroll
    for (int i = 0; i < 4; ++i) {
      int mr = wm * 64 + i * 16 + c;
      af[i] = *(const bf16x8*)&as[mr * 32 + (((quad + (mr >> 2)) & 3) * 8)];
    }
#pragma unroll
    for (int j = 0; j < 4; ++j) {
      int nr = wn * 64 + j * 16 + c;
      bfr[j] = *(const bf16x8*)&bs[nr * 32 + (((quad + (nr >> 2)) & 3) * 8)];
    }
#pragma unroll
    for (int i = 0; i < 4; ++i)
#pragma unroll
      for (int j = 0; j < 4; ++j)
        acc[i][j] = MFMA16(af[i], bfr[j], acc[i][j]);
  }
#undef OUT_STAGE

  const int nb = n0 + wn * 64;
  float bj[4];
#pragma unroll
  for (int j = 0; j < 4; ++j) bj[j] = bo[nb + j * 16 + c];
#pragma unroll
  for (int i = 0; i < 4; ++i) {
    int m = m0 + wm * 64 + i * 16 + quad * 4;
#pragma unroll
    for (int r = 0; r < 4; ++r) {
      float* orow = out + (size_t)(m + r) * 1024 + nb;
#pragma unroll
      for (int j = 0; j < 4; ++j) orow[j * 16 + c] = acc[i][j][r] + bj[j];
    }
  }
}

// ---------------------------------------------------------------------------
extern "C" void kernel_launch(void* const* d_in, const int* in_sizes, int n_in,
                              void* d_out, int out_size, void* d_ws,
                              size_t ws_size, hipStream_t stream) {
  const float* x    = (const float*)d_in[0];
  const float* rope = (const float*)d_in[1];
  const int*   mask = (const int*)d_in[2];
  const float* Wq   = (const float*)d_in[3];
  const float* bq   = (const float*)d_in[4];
  const float* Wk   = (const float*)d_in[5];
  const float* bk   = (const float*)d_in[6];
  const float* Wv   = (const float*)d_in[7];
  const float* bv   = (const float*)d_in[8];
  const float* Wo   = (const float*)d_in[9];
  const float* bo   = (const float*)d_in[10];
  float* out = (float*)d_out;

  char* ws = (char*)d_ws;
  short* xb  = (short*)(ws);               // 16 MB; reused as attout later
  short* wqb = (short*)(ws + 16777216);    // 2 MB each
  short* wkb = (short*)(ws + 18874368);
  short* wvb = (short*)(ws + 20971520);
  short* wob = (short*)(ws + 23068672);
  short* Qh  = (short*)(ws + 25198592);    // 16 MB  [bh][t][64]
  short* Kh  = (short*)(ws + 41975808);    // 16 MB  [bh][t][64]
  short* Vt  = (short*)(ws + 58753024);    // 16 MB  [bh][64][t]
  short* att = xb;  // safe: xb consumed by qkv3_gemm before attn writes

  cvt_kernel<<<12288, 256, 0, stream>>>(x, Wq, Wk, Wv, Wo, xb, wqb, wkb, wvb,
                                        wob);
  qkv3_gemm<<<dim3(64, 8), 256, 0, stream>>>(xb, wqb, wkb, wvb, bq, bk, bv,
                                             rope, mask, Qh, Kh, Vt);
  attn_kernel<<<dim3(64, 8), 256, 0, stream>>>(Qh, Kh, Vt, mask, att);
  out_gemm<<<dim3(64, 8), 256, 0, stream>>>(att, wob, bo, out);
}

// Round 9
// 252.697 us; speedup vs baseline: 1.6294x; 1.0433x over previous
//
#include <hip/hip_runtime.h>
#include <stdint.h>

// B=4, T=2048, C=1024, H=16, D=64, R=32
// Pipeline: cvt -> qkv3_gemm(fused QKV, dbuf, vectorized d-permuted Q/K
//   epilogue) -> attn(r5 structure + setprio, in-register P) -> out_gemm(128^2)
// Q/K memory layout: within each row of 64, position c*4+{0,1,2,3} holds
//   cols {c, 16+c, 32+c, 48+c} (d-permutation). QK^T contracts over d, and
//   both Q and K use the same permutation -> contraction unchanged.

typedef __attribute__((ext_vector_type(8))) short bf16x8;   // 8 bf16 (4 VGPRs)
typedef __attribute__((ext_vector_type(4))) float f32x4;    // MFMA accumulator
typedef __attribute__((ext_vector_type(4))) short short4v;  // 8-byte packed load/store

#define MFMA16(a, b, c) __builtin_amdgcn_mfma_f32_16x16x32_bf16((a), (b), (c), 0, 0, 0)

#if __has_builtin(__builtin_amdgcn_exp2f)
#define FEXP(x) __builtin_amdgcn_exp2f(x)
#define QSCALE 0.18033688011112042f  // 0.125 * log2(e)
#else
#define FEXP(x) __expf(x)
#define QSCALE 0.125f
#endif

static __device__ __forceinline__ short f2bf(float f) {
  union { float fv; uint32_t u; } v; v.fv = f;
  uint32_t r = v.u + 0x7FFFu + ((v.u >> 16) & 1u);  // RNE
  return (short)(r >> 16);
}

// pack two fp32 -> two bf16 (truncation) in one v_perm_b32
static __device__ __forceinline__ uint32_t pack_trunc(float a, float b) {
  union { float f; uint32_t u; } ua, ub;
  ua.f = a; ub.f = b;
#if __has_builtin(__builtin_amdgcn_perm)
  return __builtin_amdgcn_perm(ub.u, ua.u, 0x07060302u);
#else
  return (ub.u & 0xFFFF0000u) | (ua.u >> 16);
#endif
}

typedef __attribute__((address_space(1))) void as1_void;
typedef __attribute__((address_space(3))) void as3_void;
static __device__ __forceinline__ void gld_lds16(const void* g, void* l) {
  __builtin_amdgcn_global_load_lds((as1_void*)g, (as3_void*)l, 16, 0, 0);
}

// ---------------------------------------------------------------------------
// Kernel 1: fp32 -> bf16 conversion for x, Wq, Wk, Wv, Wo
// ---------------------------------------------------------------------------
__global__ __launch_bounds__(256) void cvt_kernel(
    const float* x, const float* wq, const float* wk, const float* wv,
    const float* wo,
    short* xb, short* wqb, short* wkb, short* wvb, short* wob) {
  int64_t g = (int64_t)blockIdx.x * 256 + threadIdx.x;  // unit = 4 floats
  const int64_t NX = 8388608 / 4, NW = 1048576 / 4;
  const float* src;
  short* dst;
  int64_t i;
  if (g < NX)               { src = x;  dst = xb;  i = g; }
  else if (g < NX + NW)     { src = wq; dst = wqb; i = g - NX; }
  else if (g < NX + 2 * NW) { src = wk; dst = wkb; i = g - NX - NW; }
  else if (g < NX + 3 * NW) { src = wv; dst = wvb; i = g - NX - 2 * NW; }
  else                      { src = wo; dst = wob; i = g - NX - 3 * NW; }
  float4 v = ((const float4*)src)[i];
  short4v o;
  o[0] = f2bf(v.x); o[1] = f2bf(v.y); o[2] = f2bf(v.z); o[3] = f2bf(v.w);
  *(short4v*)&dst[i * 4] = o;
}

// ---------------------------------------------------------------------------
// Kernel 2: fused QKV projection (M=8192, N=1024 x3, K=1024), BK=32.
//   One A-tile stage feeds 3 B-tiles: 48 MFMA per barrier. Double-buffered
//   staging issued right after the barrier.
//   Q: scaled by QSCALE; K,V: masked rows zeroed.
//   Q,K written [bh][t][64-permuted] bf16 (pos c*4+j <- col j*16+c, one 8-B
//   store per (mat,i,r) instead of four 2-B stores); V written [bh][64][t].
// ---------------------------------------------------------------------------
__global__ __launch_bounds__(256, 2) void qkv3_gemm(
    const short* __restrict__ Xb,
    const short* __restrict__ Wq, const short* __restrict__ Wk,
    const short* __restrict__ Wv,
    const float* __restrict__ bq, const float* __restrict__ bk,
    const float* __restrict__ bv,
    const float* __restrict__ rope, const int* __restrict__ mask,
    short* __restrict__ Qh, short* __restrict__ Kh, short* __restrict__ Vt) {
  __shared__ __align__(16) short As[2][128 * 32];     // 16 KB
  __shared__ __align__(16) short Bs[2][3][128 * 32];  // 48 KB

  const int t = threadIdx.x;
  const int lane = t & 63;
  const int wave = t >> 6;
  const int c = lane & 15;
  const int quad = lane >> 4;
  const int m0 = blockIdx.x * 128;
  const int n0 = blockIdx.y * 128;

  f32x4 zero4 = {0.f, 0.f, 0.f, 0.f};
  f32x4 acc[3][4][4];
#pragma unroll
  for (int m = 0; m < 3; ++m)
#pragma unroll
    for (int i = 0; i < 4; ++i)
#pragma unroll
      for (int j = 0; j < 4; ++j) acc[m][i][j] = zero4;

  const int wm = wave & 1, wn = wave >> 1;

  const int srow = t >> 2;
  const int gc = ((t & 3) - (srow >> 2)) & 3;
  const short* gA = Xb + (size_t)(m0 + srow) * 1024 + gc * 8;
  const short* gW0 = Wq + (size_t)(n0 + srow) * 1024 + gc * 8;
  const short* gW1 = Wk + (size_t)(n0 + srow) * 1024 + gc * 8;
  const short* gW2 = Wv + (size_t)(n0 + srow) * 1024 + gc * 8;

#define QKV_STAGE(buf, k0)                                  \
  do {                                                      \
    gld_lds16(gA + (k0), &As[buf][t * 8]);                  \
    gld_lds16(gA + (k0) + 65536, &As[buf][t * 8 + 2048]);   \
    gld_lds16(gW0 + (k0), &Bs[buf][0][t * 8]);              \
    gld_lds16(gW0 + (k0) + 65536, &Bs[buf][0][t * 8 + 2048]); \
    gld_lds16(gW1 + (k0), &Bs[buf][1][t * 8]);              \
    gld_lds16(gW1 + (k0) + 65536, &Bs[buf][1][t * 8 + 2048]); \
    gld_lds16(gW2 + (k0), &Bs[buf][2][t * 8]);              \
    gld_lds16(gW2 + (k0) + 65536, &Bs[buf][2][t * 8 + 2048]); \
  } while (0)

  QKV_STAGE(0, 0);

  for (int ki = 0; ki < 32; ++ki) {
    __syncthreads();  // drains buf[ki&1] loads (issued one compute phase ago)
    if (ki < 31) QKV_STAGE((ki + 1) & 1, (ki + 1) * 32);

    const short* as = &As[ki & 1][0];
    bf16x8 af[4];
#pragma unroll
    for (int i = 0; i < 4; ++i) {
      int mr = wm * 64 + i * 16 + c;
      af[i] = *(const bf16x8*)&as[mr * 32 + (((quad + (mr >> 2)) & 3) * 8)];
    }
#pragma unroll
    for (int m = 0; m < 3; ++m) {
      const short* bs = &Bs[ki & 1][m][0];
      bf16x8 bfr[4];
#pragma unroll
      for (int j = 0; j < 4; ++j) {
        int nr = wn * 64 + j * 16 + c;
        bfr[j] = *(const bf16x8*)&bs[nr * 32 + (((quad + (nr >> 2)) & 3) * 8)];
      }
#pragma unroll
      for (int i = 0; i < 4; ++i)
#pragma unroll
        for (int j = 0; j < 4; ++j)
          acc[m][i][j] = MFMA16(af[i], bfr[j], acc[m][i][j]);
    }
  }
#undef QKV_STAGE

  // ---- epilogue: C/D layout col=lane&15, row=quad*4+reg ----
  const int nb = n0 + wn * 64;  // wave's 64 cols == one head
  const int hcol = nb >> 6;
  const int bidx = m0 >> 11;
  const int tbase = (m0 & 2047) + wm * 64 + quad * 4;
  const int* mrow = mask + bidx * 2048;
  const size_t hb = (size_t)(bidx * 16 + hcol) * 2048;

  // mask -> registers (4 int4 loads instead of 16 scalar loads)
  float frm[4][4];
#pragma unroll
  for (int i = 0; i < 4; ++i) {
    int4 mv = *(const int4*)&mrow[tbase + i * 16];
    frm[i][0] = mv.x ? 1.f : 0.f; frm[i][1] = mv.y ? 1.f : 0.f;
    frm[i][2] = mv.z ? 1.f : 0.f; frm[i][3] = mv.w ? 1.f : 0.f;
  }

  // Q and K: permuted [bh][t][64] with RoPE, one 8-B store per (mat,i,r)
  {
    float bjq[4], bjk[4];
#pragma unroll
    for (int j = 0; j < 4; ++j) {
      bjq[j] = bq[nb + j * 16 + c];
      bjk[j] = bk[nb + j * 16 + c];
    }
#pragma unroll
    for (int i = 0; i < 4; ++i) {
#pragma unroll
      for (int r = 0; r < 4; ++r) {
        int tp = tbase + i * 16 + r;
        float cosv = rope[tp * 32 + c];
        float sinv = rope[65536 + tp * 32 + c];
        size_t base = (hb + tp) * 64 + c * 4;
        // Q
        {
          float v0 = acc[0][i][0][r] + bjq[0];
          float v1 = acc[0][i][1][r] + bjq[1];
          float v2 = acc[0][i][2][r] + bjq[2];
          float v3 = acc[0][i][3][r] + bjq[3];
          short4v o;
          o[0] = f2bf((v0 * cosv - v1 * sinv) * QSCALE);
          o[1] = f2bf((v1 * cosv + v0 * sinv) * QSCALE);
          o[2] = f2bf(v2 * QSCALE);
          o[3] = f2bf(v3 * QSCALE);
          *(short4v*)&Qh[base] = o;
        }
        // K (masked rows zeroed)
        {
          float f = frm[i][r];
          float v0 = acc[1][i][0][r] + bjk[0];
          float v1 = acc[1][i][1][r] + bjk[1];
          float v2 = acc[1][i][2][r] + bjk[2];
          float v3 = acc[1][i][3][r] + bjk[3];
          short4v o;
          o[0] = f2bf((v0 * cosv - v1 * sinv) * f);
          o[1] = f2bf((v1 * cosv + v0 * sinv) * f);
          o[2] = f2bf(v2 * f);
          o[3] = f2bf(v3 * f);
          *(short4v*)&Kh[base] = o;
        }
      }
    }
  }
  // V (mat 2): transposed [bh][d][t], masked t zeroed
  {
    float bj[4];
#pragma unroll
    for (int j = 0; j < 4; ++j) bj[j] = bv[nb + j * 16 + c];
    size_t hbv = (size_t)(bidx * 16 + hcol) * 64;
#pragma unroll
    for (int i = 0; i < 4; ++i) {
      int tp = tbase + i * 16;  // multiple of 4
#pragma unroll
      for (int j = 0; j < 4; ++j) {
        short4v pv;
#pragma unroll
        for (int r = 0; r < 4; ++r)
          pv[r] = f2bf((acc[2][i][j][r] + bj[j]) * frm[i][r]);
        size_t base = (hbv + j * 16 + c) * 2048 + tp;
        *(short4v*)&Vt[base] = pv;
      }
    }
  }
}

// ---------------------------------------------------------------------------
// Kernel 3: attention, static softmax, IN-REGISTER P (r5 structure, best
//   measured 76.5us) + T5 setprio around MFMA clusters (2 independent
//   blocks/CU at unsynchronized phases -> scheduler can favor MFMA waves).
//   K/V LDS-staged double-buffered; in-register P via k-slot assignment
//   k_phys(ks,quad,j) = (2ks+(j>>2))*16 + quad*4 + (j&3); V A-fragment
//   absorbs the permutation as two swizzled 8B LDS reads.
//   NOTE: Q/K arrive in the d-permuted row layout; all reads here are
//   position-based and identical on both operands, so nothing changes.
//   4 waves x 64 q-rows; grid (64 heads, 8 qt); bh-major = head per XCD.
// ---------------------------------------------------------------------------
__global__ __launch_bounds__(256, 2) void attn_kernel(
    const short* __restrict__ Qh, const short* __restrict__ Kh,
    const short* __restrict__ Vt, const int* __restrict__ mask,
    short* __restrict__ Og) {
  __shared__ __align__(16) short Ks[2][64 * 64];  // 16 KB
  __shared__ __align__(16) short Vs[2][64 * 64];  // 16 KB

  const int t = threadIdx.x;
  const int lane = t & 63;
  const int wave = t >> 6;  // 0..3
  const int c = lane & 15;
  const int quad = lane >> 4;
  const int bh = blockIdx.x;   // 0..63 (x-major: head -> fixed XCD)
  const int qt = blockIdx.y;   // 0..7 (256 q rows each)
  const int bidx = bh >> 4;
  const short* Qg = Qh + ((size_t)bh * 2048 + qt * 256) * 64;
  const short* Kg = Kh + (size_t)bh * 2048 * 64;
  const short* Vg = Vt + (size_t)bh * 64 * 2048;

  // count masked keys for this batch; full butterfly so every lane holds the
  // total (in-register, no LDS scalar / extra barrier dependence)
  float nm;
  {
    const int4* mr = (const int4*)(mask + bidx * 2048);
    int cnt = 0;
#pragma unroll
    for (int k = 0; k < 8; ++k) {
      int4 a = mr[k * 64 + lane];
      cnt += (a.x == 0) + (a.y == 0) + (a.z == 0) + (a.w == 0);
    }
    cnt += __shfl_xor(cnt, 1);  cnt += __shfl_xor(cnt, 2);
    cnt += __shfl_xor(cnt, 4);  cnt += __shfl_xor(cnt, 8);
    cnt += __shfl_xor(cnt, 16); cnt += __shfl_xor(cnt, 32);
    nm = (float)cnt;
  }

  // Q fragments (B-operand), loop-invariant; wave covers 64 q rows (it 0..3)
  bf16x8 qf[2][4];
#pragma unroll
  for (int ks = 0; ks < 2; ++ks)
#pragma unroll
    for (int it = 0; it < 4; ++it)
      qf[ks][it] =
          *(const bf16x8*)&Qg[(wave * 64 + it * 16 + c) * 64 + ks * 32 + quad * 8];

  const bf16x8 ones = {0x3F80, 0x3F80, 0x3F80, 0x3F80,
                       0x3F80, 0x3F80, 0x3F80, 0x3F80};  // bf16 1.0 x8

  f32x4 zero4 = {0.f, 0.f, 0.f, 0.f};
  f32x4 O[4][4];
#pragma unroll
  for (int dt = 0; dt < 4; ++dt)
#pragma unroll
    for (int it = 0; it < 4; ++it) O[dt][it] = zero4;
  f32x4 Ol[4] = {zero4, zero4, zero4, zero4};

  // staging: 256 threads x 4 x 16B = 64x64 K tile + 64x64 V tile per chunk
  const int krow0 = t >> 3;                 // 0..31
  const int klc = (t & 7) ^ (krow0 & 7);    // XOR-swizzled 16B col block
  const short* gk0 = Kg + (size_t)krow0 * 64 + klc * 8;
  const short* gv0 = Vg + (size_t)krow0 * 2048 + klc * 8;

  // prologue: stage chunk 0 into buffer 0
  gld_lds16(gk0, &Ks[0][t * 8]);
  gld_lds16(gk0 + 32 * 64, &Ks[0][t * 8 + 2048]);
  gld_lds16(gv0, &Vs[0][t * 8]);
  gld_lds16(gv0 + 32 * 2048, &Vs[0][t * 8 + 2048]);

  const int s2 = (c & 7) * 2;  // 8B-unit swizzle for V fragment reads

  for (int ci = 0; ci < 32; ++ci) {
    __syncthreads();  // drains chunk-ci loads (issued one compute-phase ago)
    if (ci < 31) {
      int cn = (ci + 1) * 64;
      int nb = (ci + 1) & 1;
      gld_lds16(gk0 + (size_t)cn * 64, &Ks[nb][t * 8]);
      gld_lds16(gk0 + (size_t)(cn + 32) * 64, &Ks[nb][t * 8 + 2048]);
      gld_lds16(gv0 + cn, &Vs[nb][t * 8]);
      gld_lds16(gv0 + cn + 32 * 2048, &Vs[nb][t * 8 + 2048]);
    }
    const short* ksb = &Ks[ci & 1][0];
    const short* vsb = &Vs[ci & 1][0];

    // hoisted K fragments (A-operand of S^T), contiguous 16B swizzled blocks
    bf16x8 ak[2][4];
#pragma unroll
    for (int ks = 0; ks < 2; ++ks)
#pragma unroll
      for (int jt = 0; jt < 4; ++jt)
        ak[ks][jt] = *(const bf16x8*)&ksb[(jt * 16 + c) * 64 +
                                          (((4 * ks + quad) ^ (c & 7)) * 8)];

    // hoisted V fragments (A-operand of PV) under the k-slot permutation:
    // slot j of av[ks][dt] = V^T[dt*16+c][(2ks+(j>>2))*16 + quad*4 + (j&3)]
    // -> two 8B groups at swizzled units u and u^4.
    bf16x8 av[2][4];
#pragma unroll
    for (int ks = 0; ks < 2; ++ks)
#pragma unroll
      for (int dt = 0; dt < 4; ++dt) {
        int u = (8 * ks + quad) ^ s2;
        int rowb = (dt * 16 + c) * 64;
        short4v lo = *(const short4v*)&vsb[rowb + u * 4];
        short4v hi = *(const short4v*)&vsb[rowb + (u ^ 4) * 4];
        union { short4v h[2]; bf16x8 v; } uu;
        uu.h[0] = lo; uu.h[1] = hi;
        av[ks][dt] = uu.v;
      }

#pragma unroll
    for (int it = 0; it < 4; ++it) {  // four 16-row q sub-blocks
      f32x4 St[4];
      __builtin_amdgcn_s_setprio(1);
#pragma unroll
      for (int jt = 0; jt < 4; ++jt)
        St[jt] = MFMA16(ak[0][jt], qf[0][it], zero4);
#pragma unroll
      for (int jt = 0; jt < 4; ++jt)
        St[jt] = MFMA16(ak[1][jt], qf[1][it], St[jt]);
      __builtin_amdgcn_s_setprio(0);

      // exp2 + pack -> PV B-fragments, entirely in-register.
      bf16x8 bp[2];
#pragma unroll
      for (int ks = 0; ks < 2; ++ks) {
        union { uint32_t w[4]; bf16x8 v; } uu;
        uu.w[0] = pack_trunc(FEXP(St[2 * ks][0]),     FEXP(St[2 * ks][1]));
        uu.w[1] = pack_trunc(FEXP(St[2 * ks][2]),     FEXP(St[2 * ks][3]));
        uu.w[2] = pack_trunc(FEXP(St[2 * ks + 1][0]), FEXP(St[2 * ks + 1][1]));
        uu.w[3] = pack_trunc(FEXP(St[2 * ks + 1][2]), FEXP(St[2 * ks + 1][3]));
        bp[ks] = uu.v;
      }

      __builtin_amdgcn_s_setprio(1);
#pragma unroll
      for (int ks = 0; ks < 2; ++ks) {
        Ol[it] = MFMA16(ones, bp[ks], Ol[it]);
#pragma unroll
        for (int dt = 0; dt < 4; ++dt)
          O[dt][it] = MFMA16(av[ks][dt], bp[ks], O[dt][it]);
      }
      __builtin_amdgcn_s_setprio(0);
    }
  }

#pragma unroll
  for (int it = 0; it < 4; ++it) {
    float inv = 1.0f / (Ol[it][0] - nm);  // remove masked keys' exp2(0)=1
    int tq = qt * 256 + wave * 64 + it * 16 + c;
    size_t rb = ((size_t)bidx * 2048 + tq) * 1024 + (size_t)(bh & 15) * 64;
#pragma unroll
    for (int dt = 0; dt < 4; ++dt) {
      short4v ov;
#pragma unroll
      for (int r = 0; r < 4; ++r) ov[r] = f2bf(O[dt][it][r] * inv);
      *(short4v*)&Og[rb + dt * 16 + quad * 4] = ov;
    }
  }
}

// ---------------------------------------------------------------------------
// Kernel 4: output projection GEMM: 128x128 tile (qkv3 structure, one B).
//   16 MFMA per wave per K-step on 8 b128 LDS reads. Grid (64,8)=512 blocks,
//   32 KB LDS, 2 blocks/CU. out = attout @ Wo^T + bo (fp32 out).
// ---------------------------------------------------------------------------
__global__ __launch_bounds__(256, 2) void out_gemm(
    const short* __restrict__ Ab, const short* __restrict__ Wob,
    const float* __restrict__ bo, float* __restrict__ out) {
  __shared__ __align__(16) short As[2][128 * 32];  // 16 KB
  __shared__ __align__(16) short Bs[2][128 * 32];  // 16 KB

  const int t = threadIdx.x;
  const int lane = t & 63;
  const int wave = t >> 6;
  const int c = lane & 15;
  const int quad = lane >> 4;
  const int m0 = blockIdx.x * 128;
  const int n0 = blockIdx.y * 128;

  f32x4 zero4 = {0.f, 0.f, 0.f, 0.f};
  f32x4 acc[4][4];
#pragma unroll
  for (int i = 0; i < 4; ++i)
#pragma unroll
    for (int j = 0; j < 4; ++j) acc[i][j] = zero4;

  const int wm = wave & 1, wn = wave >> 1;

  const int srow = t >> 2;
  const int gc = ((t & 3) - (srow >> 2)) & 3;
  const short* gA = Ab + (size_t)(m0 + srow) * 1024 + gc * 8;
  const short* gB = Wob + (size_t)(n0 + srow) * 1024 + gc * 8;

#define OUT_STAGE(buf, k0)                                 \
  do {                                                     \
    gld_lds16(gA + (k0), &As[buf][t * 8]);                 \
    gld_lds16(gA + (k0) + 65536, &As[buf][t * 8 + 2048]);  \
    gld_lds16(gB + (k0), &Bs[buf][t * 8]);                 \
    gld_lds16(gB + (k0) + 65536, &Bs[buf][t * 8 + 2048]);  \
  } while (0)

  OUT_STAGE(0, 0);

  for (int ki = 0; ki < 32; ++ki) {
    __syncthreads();
    if (ki < 31) OUT_STAGE((ki + 1) & 1, (ki + 1) * 32);

    const short* as = &As[ki & 1][0];
    const short* bs = &Bs[ki & 1][0];
    bf16x8 af[4], bfr[4];
#pragma unroll
    for (int i = 0; i < 4; ++i) {
      int mr = wm * 64 + i * 16 + c;
      af[i] = *(const bf16x8*)&as[mr * 32 + (((quad + (mr >> 2)) & 3) * 8)];
    }
#pragma unroll
    for (int j = 0; j < 4; ++j) {
      int nr = wn * 64 + j * 16 + c;
      bfr[j] = *(const bf16x8*)&bs[nr * 32 + (((quad + (nr >> 2)) & 3) * 8)];
    }
#pragma unroll
    for (int i = 0; i < 4; ++i)
#pragma unroll
      for (int j = 0; j < 4; ++j)
        acc[i][j] = MFMA16(af[i], bfr[j], acc[i][j]);
  }
#undef OUT_STAGE

  const int nb = n0 + wn * 64;
  float bj[4];
#pragma unroll
  for (int j = 0; j < 4; ++j) bj[j] = bo[nb + j * 16 + c];
#pragma unroll
  for (int i = 0; i < 4; ++i) {
    int m = m0 + wm * 64 + i * 16 + quad * 4;
#pragma unroll
    for (int r = 0; r < 4; ++r) {
      float* orow = out + (size_t)(m + r) * 1024 + nb;
#pragma unroll
      for (int j = 0; j < 4; ++j) orow[j * 16 + c] = acc[i][j][r] + bj[j];
    }
  }
}

// ---------------------------------------------------------------------------
extern "C" void kernel_launch(void* const* d_in, const int* in_sizes, int n_in,
                              void* d_out, int out_size, void* d_ws,
                              size_t ws_size, hipStream_t stream) {
  const float* x    = (const float*)d_in[0];
  const float* rope = (const float*)d_in[1];
  const int*   mask = (const int*)d_in[2];
  const float* Wq   = (const float*)d_in[3];
  const float* bq   = (const float*)d_in[4];
  const float* Wk   = (const float*)d_in[5];
  const float* bk   = (const float*)d_in[6];
  const float* Wv   = (const float*)d_in[7];
  const float* bv   = (const float*)d_in[8];
  const float* Wo   = (const float*)d_in[9];
  const float* bo   = (const float*)d_in[10];
  float* out = (float*)d_out;

  char* ws = (char*)d_ws;
  short* xb  = (short*)(ws);               // 16 MB; reused as attout later
  short* wqb = (short*)(ws + 16777216);    // 2 MB each
  short* wkb = (short*)(ws + 18874368);
  short* wvb = (short*)(ws + 20971520);
  short* wob = (short*)(ws + 23068672);
  short* Qh  = (short*)(ws + 25198592);    // 16 MB  [bh][t][64-perm]
  short* Kh  = (short*)(ws + 41975808);    // 16 MB  [bh][t][64-perm]
  short* Vt  = (short*)(ws + 58753024);    // 16 MB  [bh][64][t]
  short* att = xb;  // safe: xb consumed by qkv3_gemm before attn writes

  cvt_kernel<<<12288, 256, 0, stream>>>(x, Wq, Wk, Wv, Wo, xb, wqb, wkb, wvb,
                                        wob);
  qkv3_gemm<<<dim3(64, 8), 256, 0, stream>>>(xb, wqb, wkb, wvb, bq, bk, bv,
                                             rope, mask, Qh, Kh, Vt);
  attn_kernel<<<dim3(64, 8), 256, 0, stream>>>(Qh, Kh, Vt, mask, att);
  out_gemm<<<dim3(64, 8), 256, 0, stream>>>(att, wob, bo, out);
}